// Round 2
// baseline (1466.015 us; speedup 1.0000x reference)
//
#include <hip/hip_runtime.h>
#include <math.h>

#define FIN  1433
#define HID  67
#define NC   7
#define NCP  8

#define BK     32
#define KTILES 45            // ceil(1433/32)
#define KPAD   (KTILES*BK)   // 1440
#define COLP   80            // 5 tiles of 16 (67 real cols, rest zero)

typedef __attribute__((ext_vector_type(8))) short short8;
typedef __attribute__((ext_vector_type(4))) float floatx4;

static __device__ inline unsigned short f2bf(float f) {
    unsigned int u = __float_as_uint(f);
    unsigned int r = (u + 0x7fffu + ((u >> 16) & 1u)) >> 16;   // RNE
    return (unsigned short)r;
}

// ---------------- CSR build ----------------

__global__ void k_zero(int* __restrict__ cnt, int N) {
    int i = blockIdx.x * 256 + threadIdx.x;
    if (i < N) cnt[i] = 0;
}

__global__ void k_count(const int* __restrict__ dst, int* __restrict__ cnt, int E) {
    int e = blockIdx.x * 256 + threadIdx.x;
    if (e < E) atomicAdd(&cnt[dst[e]], 1);
}

__global__ void k_bsum(const int* __restrict__ cnt, int* __restrict__ bsum, int N) {
    __shared__ int s[256];
    int t = threadIdx.x;
    int i = blockIdx.x * 256 + t;
    s[t] = (i < N) ? cnt[i] : 0;
    __syncthreads();
    for (int o = 128; o > 0; o >>= 1) {
        if (t < o) s[t] += s[t + o];
        __syncthreads();
    }
    if (t == 0) bsum[blockIdx.x] = s[0];
}

// exclusive scan of block sums; nb <= 512
__global__ void k_scanb(int* __restrict__ bsum, int nb) {
    __shared__ int s[512];
    int t = threadIdx.x;
    int v = (t < nb) ? bsum[t] : 0;
    s[t] = v;
    __syncthreads();
    for (int o = 1; o < 512; o <<= 1) {
        int tmp = (t >= o) ? s[t - o] : 0;
        __syncthreads();
        s[t] += tmp;
        __syncthreads();
    }
    if (t < nb) bsum[t] = s[t] - v;  // exclusive
}

__global__ void k_scan3(const int* __restrict__ cnt, const int* __restrict__ bsum,
                        int* __restrict__ rowptr, int* __restrict__ cursor,
                        float* __restrict__ dinv, int N, int E) {
    __shared__ int s[256];
    int t = threadIdx.x;
    int i = blockIdx.x * 256 + t;
    int v = (i < N) ? cnt[i] : 0;
    s[t] = v;
    __syncthreads();
    for (int o = 1; o < 256; o <<= 1) {
        int tmp = (t >= o) ? s[t - o] : 0;
        __syncthreads();
        s[t] += tmp;
        __syncthreads();
    }
    if (i < N) {
        int start = bsum[blockIdx.x] + s[t] - v;  // exclusive global prefix
        rowptr[i] = start;
        cursor[i] = start;
        dinv[i]   = rsqrtf((float)(v + 1));       // +1 self loop
    }
    if (i == 0) rowptr[N] = E;
}

__global__ void k_fill(const int* __restrict__ ei, int* __restrict__ cursor,
                       int* __restrict__ csrs, int E) {
    int e = blockIdx.x * 256 + threadIdx.x;
    if (e < E) {
        int s = ei[e];          // source
        int d = ei[E + e];      // target
        int pos = atomicAdd(&cursor[d], 1);
        csrs[pos] = s;
    }
}

// ---------------- W1 -> bf16 [col][k] padded; plus xpad = padded copy of row N-1 ----

__global__ void k_wcvt(const float* __restrict__ W1, const float* __restrict__ x,
                       unsigned short* __restrict__ Wt, float* __restrict__ xpad, int N) {
    int idx = blockIdx.x * 256 + threadIdx.x;
    if (idx < KPAD) xpad[idx] = (idx < FIN) ? x[(N - 1) * FIN + idx] : 0.f;
    if (idx >= COLP * KPAD) return;
    int col = idx / KPAD;
    int k   = idx - col * KPAD;
    float v = (col < HID && k < FIN) ? W1[k * HID + col] : 0.f;
    Wt[idx] = f2bf(v);
}

// ---------------- GEMM1 (MFMA bf16, no LDS, no barriers) ----------------
// h64[N,64] + h4[N,4] = dinv[r] * (x[N,1433] @ W1), split so agg1 gathers
// exactly 2 fully-used cache lines per row (256B-aligned) + a tiny L2-hot tail.
// Block: 64 rows, 4 waves; wave owns 16 rows (1 A-frag) -> 1563 blocks = 6/CU
// for latency hiding. A loads direct HBM->reg; B direct from L2-resident Wt.

#define GEMM1_LOAD(Abuf, KT) __builtin_memcpy(&Abuf[0], xp0 + (KT), 32)

#define GEMM1_STEP(Abuf, KT) do {                                                   \
        short8 fa;                                                                  \
        _Pragma("unroll")                                                           \
        for (int u = 0; u < 8; u++) fa[u] = (short)f2bf(Abuf[u]);                   \
        _Pragma("unroll")                                                           \
        for (int j = 0; j < 5; j++) {                                               \
            short8 bf = *(const short8*)(wb + j * 16 * KPAD + (KT));                \
            acc[j] = __builtin_amdgcn_mfma_f32_16x16x32_bf16(fa, bf, acc[j], 0, 0, 0); \
        }                                                                           \
    } while (0)

__global__ __launch_bounds__(256) void k_gemm1(const float* __restrict__ x,
                                               const unsigned short* __restrict__ Wt,
                                               const float* __restrict__ dinv,
                                               const float* __restrict__ xpad,
                                               float* __restrict__ h64,
                                               float* __restrict__ h4, int N) {
    int t    = threadIdx.x;
    int lane = t & 63;
    int w    = t >> 6;
    int lm   = lane & 15;
    int lq   = lane >> 4;
    int row0w = blockIdx.x * 64 + w * 16;

    int r0 = row0w + lm;
    // Row N-1 (and OOB tail rows) read from xpad (zero-padded to KPAD); rows
    // < N-1 over-read into the next row past k=1433, multiplied by zero B.
    const float* xp0 = (r0 >= N - 1) ? xpad : (x + r0 * FIN);
    xp0 += lq * 8;
    const unsigned short* wb = Wt + lm * KPAD + lq * 8;

    floatx4 acc[5];
#pragma unroll
    for (int j = 0; j < 5; j++) acc[j] = (floatx4){0.f, 0.f, 0.f, 0.f};

    float A0[8], A1[8];
    GEMM1_LOAD(A0, 0);
    int kt = 0;
    for (; kt + 2 * BK < KPAD; kt += 2 * BK) {   // kt = 0..1344
        GEMM1_LOAD(A1, kt + BK);
        GEMM1_STEP(A0, kt);
        GEMM1_LOAD(A0, kt + 2 * BK);
        GEMM1_STEP(A1, kt + BK);
    }
    GEMM1_STEP(A0, kt);                           // kt == 1408, tile 45

    // epilogue: C/D col=lane&15, row=lq*4+i ; pre-scale by dinv
#pragma unroll
    for (int i = 0; i < 4; i++) {
        int row = row0w + lq * 4 + i;
        if (row < N) {
            float dv = dinv[row];
            int off = row * 64;
#pragma unroll
            for (int j = 0; j < 4; j++) h64[off + j * 16 + lm] = dv * acc[j][i];
            if (lm < 4) h4[row * 4 + lm] = dv * acc[4][i];   // cols 64..67 (67 == 0)
        }
    }
}

// ---------------- agg1 + fused GEMM2 ----------------
// out1 = lrelu(b1 + dd*(h[d] + sum_e h[s]))  (h pre-scaled by dinv)
// then h2s[d][j] = dd_ignored... h2s = dinv[d] * (out1 . W2[:,j]) via 64-lane
// shfl reduction (out1 col j lives on lane j). out1 never touches memory.

__global__ __launch_bounds__(256) void k_agg1(const float* __restrict__ h64,
                                              const float* __restrict__ h4,
                                              const int* __restrict__ rowptr,
                                              const int* __restrict__ csrs,
                                              const float* __restrict__ dinv,
                                              const float* __restrict__ bias1,
                                              const float* __restrict__ W2,
                                              float* __restrict__ h2s, int N) {
    int lane = threadIdx.x & 63;
    int d = blockIdx.x * 4 + (threadIdx.x >> 6);   // wave per node
    if (d >= N) return;
    int start = rowptr[d];
    int end   = rowptr[d + 1];
    int tc = lane & 3;                              // tail col slot (64+tc)

    float m0 = 0.f, m1 = 0.f, m2 = 0.f, m3 = 0.f;
    float t0 = 0.f, t1 = 0.f, t2 = 0.f, t3 = 0.f;
    int e = start;
    for (; e + 4 <= end; e += 4) {
        int s0 = csrs[e], s1 = csrs[e + 1], s2 = csrs[e + 2], s3 = csrs[e + 3];
        m0 += h64[s0 * 64 + lane];  t0 += h4[s0 * 4 + tc];
        m1 += h64[s1 * 64 + lane];  t1 += h4[s1 * 4 + tc];
        m2 += h64[s2 * 64 + lane];  t2 += h4[s2 * 4 + tc];
        m3 += h64[s3 * 64 + lane];  t3 += h4[s3 * 4 + tc];
    }
    for (; e < end; e++) {
        int s = csrs[e];
        m0 += h64[s * 64 + lane];
        t0 += h4[s * 4 + tc];
    }
    float dd = dinv[d];
    float sa = ((m0 + m1) + (m2 + m3)) + h64[d * 64 + lane];
    float sb = ((t0 + t1) + (t2 + t3)) + h4[d * 4 + tc];

    float vm = bias1[lane] + dd * sa;               // out1 col = lane (0..63)
    vm = vm > 0.f ? vm : 0.01f * vm;
    int tcol = 64 + tc;
    float bb = (tcol < HID) ? bias1[tcol] : 0.f;
    float vt = bb + dd * sb;                        // out1 col = 64+tc (67 stays 0)
    vt = vt > 0.f ? vt : 0.01f * vt;

    // fused GEMM2: pj = sum_col out1[col]*W2[col][j]; cols 64..66 via lanes 0..2
    float pj[NC];
#pragma unroll
    for (int j = 0; j < NC; j++) {
        float wm = W2[lane * NC + j];
        float wt = (lane < 3) ? W2[(64 + lane) * NC + j] : 0.f;
        pj[j] = vm * wm + vt * wt;
    }
#pragma unroll
    for (int o = 32; o >= 1; o >>= 1) {
#pragma unroll
        for (int j = 0; j < NC; j++) pj[j] += __shfl_xor(pj[j], o);
    }
    if (lane == 0) {
        int off = d * NCP;
#pragma unroll
        for (int j = 0; j < NC; j++) h2s[off + j] = dd * pj[j];
        h2s[off + NC] = 0.f;   // pad col 7
    }
}

// ---------------- agg2 + fused log_softmax ----------------
// Wave per node: lane = (edge_slot 0..7)*8 + (col 0..7). 8 edges/iter, csrs reads
// are one contiguous 32B line. h2s pre-scaled -> no dinv in loop. shfl reductions.

__global__ __launch_bounds__(256) void k_agg2(const float* __restrict__ h2s,
                                              const int* __restrict__ rowptr,
                                              const int* __restrict__ csrs,
                                              const float* __restrict__ dinv,
                                              const float* __restrict__ b2,
                                              float* __restrict__ out, int N) {
    int lane = threadIdx.x & 63;
    int d = blockIdx.x * 4 + (threadIdx.x >> 6);   // wave per node
    if (d >= N) return;
    int es = lane >> 3;     // edge slot
    int j  = lane & 7;      // class col
    int start = rowptr[d], end = rowptr[d + 1];
    float acc = 0.f;
    for (int e = start + es; e < end; e += 8) {
        int s = csrs[e];
        acc += h2s[s * NCP + j];
    }
#pragma unroll
    for (int o = 32; o >= 8; o >>= 1) acc += __shfl_xor(acc, o);   // sum over edge slots
    float dd = dinv[d];
    float self = h2s[d * NCP + j];
    float v = ((j < NC) ? b2[j] : 0.f) + dd * (self + acc);
    // log_softmax over 7 classes (mask pad col 7)
    float mv = (j == NC) ? -1e30f : v;
#pragma unroll
    for (int o = 4; o >= 1; o >>= 1) mv = fmaxf(mv, __shfl_xor(mv, o));
    float ex = (j == NC) ? 0.f : __expf(v - mv);
    float ss = ex;
#pragma unroll
    for (int o = 4; o >= 1; o >>= 1) ss += __shfl_xor(ss, o);
    if (lane < 8 && j < NC) {
        out[d * NC + j] = v - mv - __logf(ss);
    }
}

// ---------------- launch ----------------

extern "C" void kernel_launch(void* const* d_in, const int* in_sizes, int n_in,
                              void* d_out, int out_size, void* d_ws, size_t ws_size,
                              hipStream_t stream) {
    const float* x  = (const float*)d_in[0];
    const int*   ei = (const int*)d_in[1];
    const float* W1 = (const float*)d_in[2];
    const float* b1 = (const float*)d_in[3];
    const float* W2 = (const float*)d_in[4];
    const float* b2 = (const float*)d_in[5];
    float* out = (float*)d_out;

    int N = in_sizes[0] / FIN;   // 100000
    int E = in_sizes[1] / 2;     // 3200000

    size_t o = 0;
    auto alloc = [&](size_t words) { size_t r = o; o += words; o = (o + 63) & ~(size_t)63; return r; };
    size_t o_dinv   = alloc((size_t)N);
    size_t o_cnt    = alloc((size_t)N);
    size_t o_rowptr = alloc((size_t)N + 1);
    size_t o_cursor = alloc((size_t)N);
    size_t o_bsum   = alloc(1024);
    size_t o_csrs   = alloc((size_t)E);
    size_t o_wt     = alloc((size_t)COLP * KPAD / 2);   // bf16, u32 words
    size_t o_xpad   = alloc((size_t)KPAD);
    size_t o_h64    = alloc((size_t)N * 64);            // 256B-aligned rows
    size_t o_h4     = alloc((size_t)N * 4);
    size_t o_h2s    = alloc((size_t)N * NCP);

    float* wsf = (float*)d_ws;
    int*   wsi = (int*)d_ws;
    float* dinv   = wsf + o_dinv;
    int*   cnt    = wsi + o_cnt;
    int*   rowptr = wsi + o_rowptr;
    int*   cursor = wsi + o_cursor;
    int*   bsum   = wsi + o_bsum;
    int*   csrs   = wsi + o_csrs;
    unsigned short* Wt = (unsigned short*)(wsi + o_wt);
    float* xpad   = wsf + o_xpad;
    float* h64    = wsf + o_h64;
    float* h4     = wsf + o_h4;
    float* h2s    = wsf + o_h2s;

    int nb = (N + 255) / 256;        // 391
    int eb = (E + 255) / 256;        // 12500
    int gb = (N + 63) / 64;          // 1563 blocks for gemm1 (64 rows each)

    k_zero <<<nb, 256, 0, stream>>>(cnt, N);
    k_count<<<eb, 256, 0, stream>>>(ei + E, cnt, E);
    k_bsum <<<nb, 256, 0, stream>>>(cnt, bsum, N);
    k_scanb<<<1, 512, 0, stream>>>(bsum, nb);
    k_scan3<<<nb, 256, 0, stream>>>(cnt, bsum, rowptr, cursor, dinv, N, E);
    k_fill <<<eb, 256, 0, stream>>>(ei, cursor, csrs, E);

    k_wcvt <<<(COLP * KPAD + 255) / 256, 256, 0, stream>>>(W1, x, Wt, xpad, N);
    k_gemm1<<<gb, 256, 0, stream>>>(x, Wt, dinv, xpad, h64, h4, N);
    k_agg1 <<<(N + 3) / 4, 256, 0, stream>>>(h64, h4, rowptr, csrs, dinv, b1, W2, h2s, N);
    k_agg2 <<<(N + 3) / 4, 256, 0, stream>>>(h2s, rowptr, csrs, dinv, b2, out, N);
}

// Round 3
// 1196.788 us; speedup vs baseline: 1.2250x; 1.2250x over previous
//
#include <hip/hip_runtime.h>
#include <math.h>

#define FIN  1433
#define HID  67
#define NC   7
#define NCP  8

#define BK     32
#define KTILES 45            // ceil(1433/32)
#define KPAD   (KTILES*BK)   // 1440
#define COLP   80            // 5 tiles of 16 (67 real cols, rest zero)

#define CB_BITS 9
#define CB_SIZE 512          // nodes per coarse bucket; nbk = ceil(N/512) <= 512

typedef __attribute__((ext_vector_type(8))) short short8;
typedef __attribute__((ext_vector_type(4))) float floatx4;

static __device__ inline unsigned short f2bf(float f) {
    unsigned int u = __float_as_uint(f);
    unsigned int r = (u + 0x7fffu + ((u >> 16) & 1u)) >> 16;   // RNE
    return (unsigned short)r;
}

// ---------------- W1 -> bf16 [col][k] padded; xpad = padded row N-1; zero gcnt ----

__global__ void k_wcvt(const float* __restrict__ W1, const float* __restrict__ x,
                       unsigned short* __restrict__ Wt, float* __restrict__ xpad,
                       int* __restrict__ gcnt, int N) {
    int idx = blockIdx.x * 256 + threadIdx.x;
    if (idx < 512) gcnt[idx] = 0;
    if (idx < KPAD) xpad[idx] = (idx < FIN) ? x[(N - 1) * FIN + idx] : 0.f;
    if (idx >= COLP * KPAD) return;
    int col = idx / KPAD;
    int k   = idx - col * KPAD;
    float v = (col < HID && k < FIN) ? W1[k * HID + col] : 0.f;
    Wt[idx] = f2bf(v);
}

// ---------------- CSR build, atomic-light two-level bucket sort ----------------
// Level 1: bucket edges by dst>>9 (196 coarse buckets). LDS histograms; global
// atomics only per (block, bin) for reservation (~310K total vs 6.4M before).
// Level 2: one block per bucket: LDS hist of dst&511 -> rowptr/dinv/cursors,
// then bucket-local scatter of src into csrs (64KB windows, L2-friendly).

__global__ __launch_bounds__(256) void k_cb_count(const int* __restrict__ dst,
                                                  int* __restrict__ gcnt, int E) {
    __shared__ int lh[512];
    int t = threadIdx.x;
    lh[t] = 0; lh[t + 256] = 0;
    __syncthreads();
    int base = blockIdx.x * 4096;
    for (int i = t; i < 4096; i += 256) {
        int e = base + i;
        if (e < E) atomicAdd(&lh[dst[e] >> CB_BITS], 1);
    }
    __syncthreads();
    int v0 = lh[t];       if (v0) atomicAdd(&gcnt[t], v0);
    int v1 = lh[t + 256]; if (v1) atomicAdd(&gcnt[t + 256], v1);
}

__global__ void k_cb_scan(const int* __restrict__ gcnt, int* __restrict__ cbase,
                          int* __restrict__ gcur, int E) {
    __shared__ int s[512];
    int t = threadIdx.x;                 // 512 threads
    int v = gcnt[t];
    s[t] = v;
    __syncthreads();
    for (int o = 1; o < 512; o <<= 1) {
        int tmp = (t >= o) ? s[t - o] : 0;
        __syncthreads();
        s[t] += tmp;
        __syncthreads();
    }
    int ex = s[t] - v;                   // exclusive
    cbase[t] = ex;
    gcur[t]  = ex;
    if (t == 511) cbase[512] = E;
}

__global__ __launch_bounds__(256) void k_cb_scat(const int* __restrict__ ei,
                                                 int* __restrict__ gcur,
                                                 unsigned int* __restrict__ gbuf, int E) {
    __shared__ int lh[512];
    __shared__ int gb[512];
    int t = threadIdx.x;
    lh[t] = 0; lh[t + 256] = 0;
    __syncthreads();
    int base = blockIdx.x * 4096;
    unsigned int rk[16];
    unsigned int pk[16];
#pragma unroll
    for (int i = 0; i < 16; i++) {
        int e = base + i * 256 + t;
        rk[i] = 0xFFFFFFFFu;
        if (e < E) {
            int s = ei[e];               // source
            int d = ei[E + e];           // target
            int cb = d >> CB_BITS;
            int r = atomicAdd(&lh[cb], 1);               // rank within (block,bin)
            rk[i] = (unsigned int)((cb << 16) | r);      // r < 4096 fits
            pk[i] = (unsigned int)s | ((unsigned int)(d & (CB_SIZE - 1)) << 18);
        }
    }
    __syncthreads();
    int v0 = lh[t];       gb[t]       = v0 ? atomicAdd(&gcur[t], v0) : 0;
    int v1 = lh[t + 256]; gb[t + 256] = v1 ? atomicAdd(&gcur[t + 256], v1) : 0;
    __syncthreads();
#pragma unroll
    for (int i = 0; i < 16; i++) {
        if (rk[i] != 0xFFFFFFFFu) {
            int cb = rk[i] >> 16, r = rk[i] & 0xFFFF;
            gbuf[gb[cb] + r] = pk[i];
        }
    }
}

__global__ __launch_bounds__(256) void k_cb_build(const unsigned int* __restrict__ gbuf,
                                                  const int* __restrict__ cbase,
                                                  int* __restrict__ rowptr,
                                                  int* __restrict__ csrs,
                                                  float* __restrict__ dinv, int N, int E) {
    __shared__ int hist[512];
    __shared__ int sc[512];
    int b = blockIdx.x;
    int t = threadIdx.x;
    int n0 = cbase[b], n1 = cbase[b + 1];
    hist[t] = 0; hist[t + 256] = 0;
    __syncthreads();
    for (int i = n0 + t; i < n1; i += 256)
        atomicAdd(&hist[gbuf[i] >> 18], 1);
    __syncthreads();
    sc[t] = hist[t]; sc[t + 256] = hist[t + 256];
    __syncthreads();
    for (int o = 1; o < 512; o <<= 1) {      // inclusive Hillis-Steele over 512
        int a0 = (t       >= o) ? sc[t - o]       : 0;
        int a1 = (t + 256 >= o) ? sc[t + 256 - o] : 0;
        __syncthreads();
        sc[t] += a0; sc[t + 256] += a1;
        __syncthreads();
    }
#pragma unroll
    for (int hh = 0; hh < 2; hh++) {
        int f = t + hh * 256;
        int d = (b << CB_BITS) + f;
        int cnt = hist[f];
        int ex  = sc[f] - cnt;               // exclusive prefix within bucket
        if (d < N) {
            rowptr[d] = n0 + ex;
            dinv[d]   = rsqrtf((float)(cnt + 1));   // +1 self loop
        }
    }
    if (b == 0 && t == 0) rowptr[N] = E;
    __syncthreads();
    hist[t]       = sc[t] - hist[t];         // reuse hist as scatter cursors (excl)
    hist[t + 256] = sc[t + 256] - hist[t + 256];
    __syncthreads();
    for (int i = n0 + t; i < n1; i += 256) {
        unsigned int pkd = gbuf[i];
        int f = pkd >> 18;
        int p = atomicAdd(&hist[f], 1);      // LDS atomic
        csrs[n0 + p] = (int)(pkd & 0x3FFFFu);
    }
}

// ---------------- GEMM1 (MFMA bf16, no LDS, no barriers) ----------------
// h64[N,64] + h4[N,4] = dinv[r] * (x[N,1433] @ W1). 64 rows/block, 16/wave.

#define GEMM1_LOAD(Abuf, KT) __builtin_memcpy(&Abuf[0], xp0 + (KT), 32)

#define GEMM1_STEP(Abuf, KT) do {                                                   \
        short8 fa;                                                                  \
        _Pragma("unroll")                                                           \
        for (int u = 0; u < 8; u++) fa[u] = (short)f2bf(Abuf[u]);                   \
        _Pragma("unroll")                                                           \
        for (int j = 0; j < 5; j++) {                                               \
            short8 bf = *(const short8*)(wb + j * 16 * KPAD + (KT));                \
            acc[j] = __builtin_amdgcn_mfma_f32_16x16x32_bf16(fa, bf, acc[j], 0, 0, 0); \
        }                                                                           \
    } while (0)

__global__ __launch_bounds__(256) void k_gemm1(const float* __restrict__ x,
                                               const unsigned short* __restrict__ Wt,
                                               const float* __restrict__ dinv,
                                               const float* __restrict__ xpad,
                                               float* __restrict__ h64,
                                               float* __restrict__ h4, int N) {
    int t    = threadIdx.x;
    int lane = t & 63;
    int w    = t >> 6;
    int lm   = lane & 15;
    int lq   = lane >> 4;
    int row0w = blockIdx.x * 64 + w * 16;

    int r0 = row0w + lm;
    const float* xp0 = (r0 >= N - 1) ? xpad : (x + r0 * FIN);
    xp0 += lq * 8;
    const unsigned short* wb = Wt + lm * KPAD + lq * 8;

    floatx4 acc[5];
#pragma unroll
    for (int j = 0; j < 5; j++) acc[j] = (floatx4){0.f, 0.f, 0.f, 0.f};

    float A0[8], A1[8];
    GEMM1_LOAD(A0, 0);
    int kt = 0;
    for (; kt + 2 * BK < KPAD; kt += 2 * BK) {
        GEMM1_LOAD(A1, kt + BK);
        GEMM1_STEP(A0, kt);
        GEMM1_LOAD(A0, kt + 2 * BK);
        GEMM1_STEP(A1, kt + BK);
    }
    GEMM1_STEP(A0, kt);

#pragma unroll
    for (int i = 0; i < 4; i++) {
        int row = row0w + lq * 4 + i;
        if (row < N) {
            float dv = dinv[row];
            int off = row * 64;
#pragma unroll
            for (int j = 0; j < 4; j++) h64[off + j * 16 + lm] = dv * acc[j][i];
            if (lm < 4) h4[row * 4 + lm] = dv * acc[4][i];
        }
    }
}

// ---------------- agg1 + fused GEMM2 ----------------

__global__ __launch_bounds__(256) void k_agg1(const float* __restrict__ h64,
                                              const float* __restrict__ h4,
                                              const int* __restrict__ rowptr,
                                              const int* __restrict__ csrs,
                                              const float* __restrict__ dinv,
                                              const float* __restrict__ bias1,
                                              const float* __restrict__ W2,
                                              float* __restrict__ h2s, int N) {
    int lane = threadIdx.x & 63;
    int d = blockIdx.x * 4 + (threadIdx.x >> 6);   // wave per node
    if (d >= N) return;
    int start = rowptr[d];
    int end   = rowptr[d + 1];
    int tc = lane & 3;

    float m0 = 0.f, m1 = 0.f, m2 = 0.f, m3 = 0.f;
    float t0 = 0.f, t1 = 0.f, t2 = 0.f, t3 = 0.f;
    int e = start;
    for (; e + 4 <= end; e += 4) {
        int s0 = csrs[e], s1 = csrs[e + 1], s2 = csrs[e + 2], s3 = csrs[e + 3];
        m0 += h64[s0 * 64 + lane];  t0 += h4[s0 * 4 + tc];
        m1 += h64[s1 * 64 + lane];  t1 += h4[s1 * 4 + tc];
        m2 += h64[s2 * 64 + lane];  t2 += h4[s2 * 4 + tc];
        m3 += h64[s3 * 64 + lane];  t3 += h4[s3 * 4 + tc];
    }
    for (; e < end; e++) {
        int s = csrs[e];
        m0 += h64[s * 64 + lane];
        t0 += h4[s * 4 + tc];
    }
    float dd = dinv[d];
    float sa = ((m0 + m1) + (m2 + m3)) + h64[d * 64 + lane];
    float sb = ((t0 + t1) + (t2 + t3)) + h4[d * 4 + tc];

    float vm = bias1[lane] + dd * sa;
    vm = vm > 0.f ? vm : 0.01f * vm;
    int tcol = 64 + tc;
    float bb = (tcol < HID) ? bias1[tcol] : 0.f;
    float vt = bb + dd * sb;
    vt = vt > 0.f ? vt : 0.01f * vt;

    float pj[NC];
#pragma unroll
    for (int j = 0; j < NC; j++) {
        float wm = W2[lane * NC + j];
        float wt = (lane < 3) ? W2[(64 + lane) * NC + j] : 0.f;
        pj[j] = vm * wm + vt * wt;
    }
#pragma unroll
    for (int o = 32; o >= 1; o >>= 1) {
#pragma unroll
        for (int j = 0; j < NC; j++) pj[j] += __shfl_xor(pj[j], o);
    }
    if (lane == 0) {
        int off = d * NCP;
#pragma unroll
        for (int j = 0; j < NC; j++) h2s[off + j] = dd * pj[j];
        h2s[off + NC] = 0.f;
    }
}

// ---------------- agg2 + fused log_softmax ----------------

__global__ __launch_bounds__(256) void k_agg2(const float* __restrict__ h2s,
                                              const int* __restrict__ rowptr,
                                              const int* __restrict__ csrs,
                                              const float* __restrict__ dinv,
                                              const float* __restrict__ b2,
                                              float* __restrict__ out, int N) {
    int lane = threadIdx.x & 63;
    int d = blockIdx.x * 4 + (threadIdx.x >> 6);
    if (d >= N) return;
    int es = lane >> 3;
    int j  = lane & 7;
    int start = rowptr[d], end = rowptr[d + 1];
    float acc = 0.f;
    for (int e = start + es; e < end; e += 8) {
        int s = csrs[e];
        acc += h2s[s * NCP + j];
    }
#pragma unroll
    for (int o = 32; o >= 8; o >>= 1) acc += __shfl_xor(acc, o);
    float dd = dinv[d];
    float self = h2s[d * NCP + j];
    float v = ((j < NC) ? b2[j] : 0.f) + dd * (self + acc);
    float mv = (j == NC) ? -1e30f : v;
#pragma unroll
    for (int o = 4; o >= 1; o >>= 1) mv = fmaxf(mv, __shfl_xor(mv, o));
    float ex = (j == NC) ? 0.f : __expf(v - mv);
    float ss = ex;
#pragma unroll
    for (int o = 4; o >= 1; o >>= 1) ss += __shfl_xor(ss, o);
    if (lane < 8 && j < NC) {
        out[d * NC + j] = v - mv - __logf(ss);
    }
}

// ---------------- launch ----------------

extern "C" void kernel_launch(void* const* d_in, const int* in_sizes, int n_in,
                              void* d_out, int out_size, void* d_ws, size_t ws_size,
                              hipStream_t stream) {
    const float* x  = (const float*)d_in[0];
    const int*   ei = (const int*)d_in[1];
    const float* W1 = (const float*)d_in[2];
    const float* b1 = (const float*)d_in[3];
    const float* W2 = (const float*)d_in[4];
    const float* b2 = (const float*)d_in[5];
    float* out = (float*)d_out;

    int N = in_sizes[0] / FIN;   // 100000
    int E = in_sizes[1] / 2;     // 3200000

    size_t o = 0;
    auto alloc = [&](size_t words) { size_t r = o; o += words; o = (o + 63) & ~(size_t)63; return r; };
    size_t o_dinv   = alloc((size_t)N);
    size_t o_rowptr = alloc((size_t)N + 1);
    size_t o_csrs   = alloc((size_t)E);
    size_t o_gbuf   = alloc((size_t)E);
    size_t o_gcnt   = alloc(512);
    size_t o_cbase  = alloc(513);
    size_t o_gcur   = alloc(512);
    size_t o_wt     = alloc((size_t)COLP * KPAD / 2);
    size_t o_xpad   = alloc((size_t)KPAD);
    size_t o_h64    = alloc((size_t)N * 64);
    size_t o_h4     = alloc((size_t)N * 4);
    size_t o_h2s    = alloc((size_t)N * NCP);

    float* wsf = (float*)d_ws;
    int*   wsi = (int*)d_ws;
    float* dinv   = wsf + o_dinv;
    int*   rowptr = wsi + o_rowptr;
    int*   csrs   = wsi + o_csrs;
    unsigned int* gbuf = (unsigned int*)(wsi + o_gbuf);
    int*   gcnt   = wsi + o_gcnt;
    int*   cbase  = wsi + o_cbase;
    int*   gcur   = wsi + o_gcur;
    unsigned short* Wt = (unsigned short*)(wsi + o_wt);
    float* xpad   = wsf + o_xpad;
    float* h64    = wsf + o_h64;
    float* h4     = wsf + o_h4;
    float* h2s    = wsf + o_h2s;

    int eb4 = (E + 4095) / 4096;     // 782
    int nbk = (N + CB_SIZE - 1) >> CB_BITS;   // 196
    int gb  = (N + 63) / 64;         // 1563

    k_wcvt    <<<(COLP * KPAD + 255) / 256, 256, 0, stream>>>(W1, x, Wt, xpad, gcnt, N);
    k_cb_count<<<eb4, 256, 0, stream>>>(ei + E, gcnt, E);
    k_cb_scan <<<1, 512, 0, stream>>>(gcnt, cbase, gcur, E);
    k_cb_scat <<<eb4, 256, 0, stream>>>(ei, gcur, gbuf, E);
    k_cb_build<<<nbk, 256, 0, stream>>>(gbuf, cbase, rowptr, csrs, dinv, N, E);

    k_gemm1<<<gb, 256, 0, stream>>>(x, Wt, dinv, xpad, h64, h4, N);
    k_agg1 <<<(N + 3) / 4, 256, 0, stream>>>(h64, h4, rowptr, csrs, dinv, b1, W2, h2s, N);
    k_agg2 <<<(N + 3) / 4, 256, 0, stream>>>(h2s, rowptr, csrs, dinv, b2, out, N);
}